// Round 1
// baseline (136.031 us; speedup 1.0000x reference)
//
#include <hip/hip_runtime.h>
#include <math.h>

// FeatureSqueezer: quantize (trunc(x*scale)/scale) + 3x3 median filter, reflect pad=1.
// x: (B=16, H=1024, W=1024) fp32. Memory-bound: 128 MB total traffic.

constexpr int H = 1024;
constexpr int W = 1024;
constexpr int TX = 64;   // output tile width
constexpr int TY = 16;   // output tile height
constexpr int LDS_W = TX + 2;   // 66
constexpr int LDS_H = TY + 2;   // 18

// sort2: a=min, b=max (no NaNs in input, uniform [0,1))
#define S2(a, b) { float _mn = fminf(a, b); b = fmaxf(a, b); a = _mn; }

__device__ __forceinline__ float median9(float p0, float p1, float p2,
                                         float p3, float p4, float p5,
                                         float p6, float p7, float p8) {
    // Devillard's opt_med9 — 19 compare-exchanges, returns 5th order statistic
    S2(p1, p2); S2(p4, p5); S2(p7, p8);
    S2(p0, p1); S2(p3, p4); S2(p6, p7);
    S2(p1, p2); S2(p4, p5); S2(p7, p8);
    S2(p0, p3); S2(p5, p8); S2(p4, p7);
    S2(p3, p6); S2(p1, p4); S2(p2, p5);
    S2(p4, p7); S2(p4, p2); S2(p6, p4);
    S2(p4, p2);
    return p4;
}

__global__ __launch_bounds__(256) void fsq_kernel(const float* __restrict__ x,
                                                  const int* __restrict__ bd,
                                                  float* __restrict__ out) {
    __shared__ float tile[LDS_H][LDS_W];

    const int b  = blockIdx.z;
    const int x0 = blockIdx.x * TX;
    const int y0 = blockIdx.y * TY;
    const int tid = threadIdx.x;

    const float scale = 255.0f / (float)((1 << bd[0]) - 1);

    const float* __restrict__ xb = x + (size_t)b * H * W;

    // Stage (TY+2)x(TX+2) quantized tile into LDS with reflect indexing.
    // 18*66 = 1188 elements / 256 threads = 5 iterations; interior loads coalesced.
    for (int idx = tid; idx < LDS_H * LDS_W; idx += 256) {
        int ry = idx / LDS_W;
        int rx = idx - ry * LDS_W;
        int gy = y0 - 1 + ry;
        int gx = x0 - 1 + rx;
        gy = (gy < 0) ? -gy : ((gy >= H) ? (2 * H - 2 - gy) : gy);
        gx = (gx < 0) ? -gx : ((gx >= W) ? (2 * W - 2 - gx) : gx);
        float v = xb[(size_t)gy * W + gx];
        tile[ry][rx] = truncf(v * scale) / scale;
    }
    __syncthreads();

    const int tx = tid & 63;              // 0..63 within wave -> coalesced stores
    const int tyBase = (tid >> 6) * 4;    // each thread does 4 consecutive rows

    float* __restrict__ ob = out + (size_t)b * H * W;

    #pragma unroll
    for (int i = 0; i < 4; ++i) {
        const int ty = tyBase + i;        // local output row 0..15
        // window rows ty..ty+2 in tile (tile row 0 == global row y0-1)
        float p0 = tile[ty    ][tx], p1 = tile[ty    ][tx + 1], p2 = tile[ty    ][tx + 2];
        float p3 = tile[ty + 1][tx], p4 = tile[ty + 1][tx + 1], p5 = tile[ty + 1][tx + 2];
        float p6 = tile[ty + 2][tx], p7 = tile[ty + 2][tx + 1], p8 = tile[ty + 2][tx + 2];
        float m = median9(p0, p1, p2, p3, p4, p5, p6, p7, p8);
        ob[(size_t)(y0 + ty) * W + (x0 + tx)] = m;
    }
}

extern "C" void kernel_launch(void* const* d_in, const int* in_sizes, int n_in,
                              void* d_out, int out_size, void* d_ws, size_t ws_size,
                              hipStream_t stream) {
    const float* x  = (const float*)d_in[0];
    const int*   bd = (const int*)d_in[1];
    float*       out = (float*)d_out;

    const int B = in_sizes[0] / (H * W);   // 16
    dim3 grid(W / TX, H / TY, B);          // (16, 64, 16)
    fsq_kernel<<<grid, 256, 0, stream>>>(x, bd, out);
}

// Round 2
// 115.965 us; speedup vs baseline: 1.1730x; 1.1730x over previous
//
#include <hip/hip_runtime.h>
#include <math.h>

// FeatureSqueezer: quantize trunc(x*scale)/scale + 3x3 median, reflect pad=1.
// x: (16, 1024, 1024) fp32. Memory-bound target: 128 MB -> ~20 us @ 6.3 TB/s.
//
// Layout: block = 256 threads covers a full 1024-wide row strip, TY=8 output
// rows. Thread t owns output cols 4t..4t+3. Staged tile = 10 quantized rows
// in LDS (full width + 2 halo slots at cols 1024/1025). Vertical rolling
// window reuses sorted row-triples (3 CE/row + 10 CE merge per pixel).

constexpr int H = 1024;
constexpr int W = 1024;
constexpr int TY = 8;            // output rows per block
constexpr int NROWS = TY + 2;    // staged rows incl. vertical halo
constexpr int LDSW = 1028;       // row stride in floats; 1028*4 = 4112 B (16B multiple)

#define S2(a, b) { float _mn = fminf(a, b); b = fmaxf(a, b); a = _mn; }

__device__ __forceinline__ void sort3(float& a, float& b, float& c) {
    S2(a, b); S2(b, c); S2(a, b);   // ascending
}

// Each input triple already sorted ascending: (p0<=p1<=p2), (p3<=p4<=p5), (p6<=p7<=p8).
// Remaining 10 compare-exchanges of Devillard's opt_med9.
__device__ __forceinline__ float merge9(float p0, float p1, float p2,
                                        float p3, float p4, float p5,
                                        float p6, float p7, float p8) {
    S2(p0, p3); S2(p5, p8); S2(p4, p7);
    S2(p3, p6); S2(p1, p4); S2(p2, p5);
    S2(p4, p7); S2(p4, p2); S2(p6, p4);
    S2(p4, p2);
    return p4;
}

__global__ __launch_bounds__(256) void fsq_kernel(const float* __restrict__ x,
                                                  const int* __restrict__ bdp,
                                                  float* __restrict__ out) {
    __shared__ float tile[NROWS * LDSW];

    const int t  = threadIdx.x;            // 0..255 -> output cols 4t..4t+3
    const int y0 = blockIdx.x * TY;
    const int b  = blockIdx.y;

    const float q     = (float)((1 << bdp[0]) - 1);
    const float scale = 255.0f / q;
    const float rinv  = q / 255.0f;        // ~1/scale; error << threshold

    const size_t base = (size_t)b * H * W;
    const float* __restrict__ xb = x + base;
    float* __restrict__ ob       = out + base;

    // ---- stage NROWS quantized rows (coalesced float4, interior) ----
    #pragma unroll
    for (int r = 0; r < NROWS; ++r) {
        int gy = y0 - 1 + r;
        gy = (gy < 0) ? 1 : ((gy >= H) ? 2 * H - 2 - gy : gy);   // reflect pad=1
        const float4 v = *(const float4*)(xb + (size_t)gy * W + 4 * t);
        float4 qv;
        qv.x = truncf(v.x * scale) * rinv;
        qv.y = truncf(v.y * scale) * rinv;
        qv.z = truncf(v.z * scale) * rinv;
        qv.w = truncf(v.w * scale) * rinv;
        *(float4*)(&tile[r * LDSW + 4 * t]) = qv;                // 16B-aligned ds_write_b128
    }
    // halo slots: col 1024 = global col 1024 -> reflect 1022 (right),
    //             col 1025 = global col  -1 -> reflect 1    (left)
    if (t < 2 * NROWS) {
        int r = t >> 1, side = t & 1;
        int gy = y0 - 1 + r;
        gy = (gy < 0) ? 1 : ((gy >= H) ? 2 * H - 2 - gy : gy);
        int gx = side ? 1 : 1022;
        tile[r * LDSW + 1024 + side] = truncf(xb[(size_t)gy * W + gx] * scale) * rinv;
    }
    __syncthreads();

    // window cols for thread t: global 4t-1 .. 4t+4
    const int cL = (t == 0) ? 1025 : (4 * t - 1);   // left neighbor (halo slot if t==0)
    const int cR = 4 * t + 4;                       // ==1024 (right halo slot) when t==255

    float s0[4][3], s1[4][3], s2[4][3];
    float v[6];

    auto loadrow = [&](int r, float* vv) {
        const float* row = &tile[r * LDSW];
        float4 m = *(const float4*)(row + 4 * t);   // ds_read_b128, 16B-aligned
        vv[0] = row[cL];
        vv[1] = m.x; vv[2] = m.y; vv[3] = m.z; vv[4] = m.w;
        vv[5] = row[cR];
    };

    // prime rows 0,1
    loadrow(0, v);
    #pragma unroll
    for (int c = 0; c < 4; ++c) {
        s0[c][0] = v[c]; s0[c][1] = v[c + 1]; s0[c][2] = v[c + 2];
        sort3(s0[c][0], s0[c][1], s0[c][2]);
    }
    loadrow(1, v);
    #pragma unroll
    for (int c = 0; c < 4; ++c) {
        s1[c][0] = v[c]; s1[c][1] = v[c + 1]; s1[c][2] = v[c + 2];
        sort3(s1[c][0], s1[c][1], s1[c][2]);
    }

    // roll down: tile row r completes the window centered at output row y0+r-2
    #pragma unroll
    for (int r = 2; r < NROWS; ++r) {
        loadrow(r, v);
        #pragma unroll
        for (int c = 0; c < 4; ++c) {
            s2[c][0] = v[c]; s2[c][1] = v[c + 1]; s2[c][2] = v[c + 2];
            sort3(s2[c][0], s2[c][1], s2[c][2]);
        }
        float4 o;
        o.x = merge9(s0[0][0], s0[0][1], s0[0][2], s1[0][0], s1[0][1], s1[0][2], s2[0][0], s2[0][1], s2[0][2]);
        o.y = merge9(s0[1][0], s0[1][1], s0[1][2], s1[1][0], s1[1][1], s1[1][2], s2[1][0], s2[1][1], s2[1][2]);
        o.z = merge9(s0[2][0], s0[2][1], s0[2][2], s1[2][0], s1[2][1], s1[2][2], s2[2][0], s2[2][1], s2[2][2]);
        o.w = merge9(s0[3][0], s0[3][1], s0[3][2], s1[3][0], s1[3][1], s1[3][2], s2[3][0], s2[3][1], s2[3][2]);
        *(float4*)(ob + (size_t)(y0 + r - 2) * W + 4 * t) = o;   // global_store_dwordx4

        #pragma unroll
        for (int c = 0; c < 4; ++c) {
            #pragma unroll
            for (int k = 0; k < 3; ++k) { s0[c][k] = s1[c][k]; s1[c][k] = s2[c][k]; }
        }
    }
}

extern "C" void kernel_launch(void* const* d_in, const int* in_sizes, int n_in,
                              void* d_out, int out_size, void* d_ws, size_t ws_size,
                              hipStream_t stream) {
    const float* x  = (const float*)d_in[0];
    const int*   bd = (const int*)d_in[1];
    float*       out = (float*)d_out;

    const int B = in_sizes[0] / (H * W);   // 16
    dim3 grid(H / TY, B);                  // (128, 16)
    fsq_kernel<<<grid, 256, 0, stream>>>(x, bd, out);
}

// Round 3
// 114.792 us; speedup vs baseline: 1.1850x; 1.0102x over previous
//
#include <hip/hip_runtime.h>
#include <math.h>

// FeatureSqueezer: quantize trunc(x*scale)/scale + 3x3 median, reflect pad=1.
// x: (16, 1024, 1024) fp32. HBM floor: 128 MB -> ~20 us @ 6.3 TB/s.
//
// Median via column-sorted identity using gfx950 3-input VALU ops:
//   sorted cols (lo,mid,hi) = (v_min3, v_med3, v_max3) of the vertical triple
//   med9 = med3( max3(lows), med3(mids), min3(highs) )
// => 3 instr/column-sort + 4 instr/pixel-merge (vs 19-CE network = 38 ops).

constexpr int H = 1024;
constexpr int W = 1024;
constexpr int TY = 8;            // output rows per block
constexpr int NROWS = TY + 2;    // staged rows incl. vertical halo
constexpr int LDSW = 1028;       // row stride in floats (cols 1024/1025 = R/L halo)

__device__ __forceinline__ float min3f(float a, float b, float c) { return fminf(a, fminf(b, c)); }
__device__ __forceinline__ float max3f(float a, float b, float c) { return fmaxf(a, fmaxf(b, c)); }
__device__ __forceinline__ float med3f(float a, float b, float c) { return __builtin_amdgcn_fmed3f(a, b, c); }

__global__ __launch_bounds__(256) void fsq_kernel(const float* __restrict__ x,
                                                  const int* __restrict__ bdp,
                                                  float* __restrict__ out) {
    __shared__ float tile[NROWS * LDSW];

    const int t  = threadIdx.x;            // 0..255 -> output cols 4t..4t+3
    const int y0 = blockIdx.x * TY;
    const int b  = blockIdx.y;

    const float q     = (float)((1 << bdp[0]) - 1);
    const float scale = 255.0f / q;
    const float rinv  = q / 255.0f;        // ~1/scale; quant error << 1.98e-2 threshold

    const size_t base = (size_t)b * H * W;
    const float* __restrict__ xb = x + base;
    float* __restrict__ ob       = out + base;

    // ---- stage NROWS quantized rows (coalesced float4) ----
    #pragma unroll
    for (int r = 0; r < NROWS; ++r) {
        int gy = y0 - 1 + r;
        gy = (gy < 0) ? 1 : ((gy >= H) ? 2 * H - 2 - gy : gy);   // reflect pad=1
        const float4 v = *(const float4*)(xb + (size_t)gy * W + 4 * t);
        float4 qv;
        qv.x = truncf(v.x * scale) * rinv;
        qv.y = truncf(v.y * scale) * rinv;
        qv.z = truncf(v.z * scale) * rinv;
        qv.w = truncf(v.w * scale) * rinv;
        *(float4*)(&tile[r * LDSW + 4 * t]) = qv;                // ds_write_b128
    }
    // halo: col 1024 <- global col 1024 reflect-> 1022; col 1025 <- col -1 -> 1
    if (t < 2 * NROWS) {
        int r = t >> 1, side = t & 1;
        int gy = y0 - 1 + r;
        gy = (gy < 0) ? 1 : ((gy >= H) ? 2 * H - 2 - gy : gy);
        int gx = side ? 1 : 1022;
        tile[r * LDSW + 1024 + side] = truncf(xb[(size_t)gy * W + gx] * scale) * rinv;
    }
    __syncthreads();

    // window cols for thread t: global 4t-1 .. 4t+4 (6 columns)
    const int cL = (t == 0) ? 1025 : (4 * t - 1);
    const int cR = 4 * t + 4;                       // ==1024 (right halo) when t==255

    float r0[6], r1[6], r2[6];

    auto loadrow = [&](int r, float* vv) {
        const float* row = &tile[r * LDSW];
        float4 m = *(const float4*)(row + 4 * t);   // ds_read_b128
        vv[0] = row[cL];
        vv[1] = m.x; vv[2] = m.y; vv[3] = m.z; vv[4] = m.w;
        vv[5] = row[cR];
    };

    loadrow(0, r0);
    loadrow(1, r1);

    #pragma unroll
    for (int r = 2; r < NROWS; ++r) {
        loadrow(r, r2);

        // sort 6 vertical triples: 3 instr each (v_min3/v_med3/v_max3)
        float lo[6], mi[6], hi[6];
        #pragma unroll
        for (int c = 0; c < 6; ++c) {
            lo[c] = min3f(r0[c], r1[c], r2[c]);
            mi[c] = med3f(r0[c], r1[c], r2[c]);
            hi[c] = max3f(r0[c], r1[c], r2[c]);
        }

        // merge: med9 = med3( max3(lows), med3(mids), min3(highs) ) -- 4 instr/px
        float4 o;
        o.x = med3f(max3f(lo[0], lo[1], lo[2]), med3f(mi[0], mi[1], mi[2]), min3f(hi[0], hi[1], hi[2]));
        o.y = med3f(max3f(lo[1], lo[2], lo[3]), med3f(mi[1], mi[2], mi[3]), min3f(hi[1], hi[2], hi[3]));
        o.z = med3f(max3f(lo[2], lo[3], lo[4]), med3f(mi[2], mi[3], mi[4]), min3f(hi[2], hi[3], hi[4]));
        o.w = med3f(max3f(lo[3], lo[4], lo[5]), med3f(mi[3], mi[4], mi[5]), min3f(hi[3], hi[4], hi[5]));
        *(float4*)(ob + (size_t)(y0 + r - 2) * W + 4 * t) = o;   // global_store_dwordx4

        #pragma unroll
        for (int c = 0; c < 6; ++c) { r0[c] = r1[c]; r1[c] = r2[c]; }  // elided by unroll
    }
}

extern "C" void kernel_launch(void* const* d_in, const int* in_sizes, int n_in,
                              void* d_out, int out_size, void* d_ws, size_t ws_size,
                              hipStream_t stream) {
    const float* x  = (const float*)d_in[0];
    const int*   bd = (const int*)d_in[1];
    float*       out = (float*)d_out;

    const int B = in_sizes[0] / (H * W);   // 16
    dim3 grid(H / TY, B);                  // (128, 16)
    fsq_kernel<<<grid, 256, 0, stream>>>(x, bd, out);
}